// Round 9
// baseline (300.793 us; speedup 1.0000x reference)
//
#include <hip/hip_runtime.h>
#include <hip/hip_bf16.h>
#include <stdint.h>

#define N_TOK 8192
#define DIN   1024
#define DOUT  1024
#define HID   1024
#define NE    8
#define CAP   0.8f   // 1 - EPS

typedef __attribute__((ext_vector_type(8))) short short8;
typedef __attribute__((ext_vector_type(4))) float floatx4;

__device__ __forceinline__ void async_load16(const void* g, void* l) {
  __builtin_amdgcn_global_load_lds(
      (const __attribute__((address_space(1))) void*)g,
      (__attribute__((address_space(3))) void*)l,
      16, 0, 0);
}

__device__ __forceinline__ unsigned short bf16_bits(float f) {
  return __builtin_bit_cast(unsigned short, __float2bfloat16(f));
}

// ---------------------------------------------------------------------------
// Selector, COALESCED-Wsel version (round-5, measured good). Unchanged.
// ---------------------------------------------------------------------------
__global__ __launch_bounds__(256) void selector_kernel(
    const float* __restrict__ x, const float* __restrict__ Wsel,
    const float* __restrict__ bsel,
    __hip_bfloat16* __restrict__ x_bf, float* __restrict__ sw,
    float4* __restrict__ out4)
{
  {
    const int base = blockIdx.x * 4096 + threadIdx.x;
    const float4 z4 = {0.f, 0.f, 0.f, 0.f};
#pragma unroll
    for (int r = 0; r < 16; r++) out4[base + r * 256] = z4;
  }

  const int lane = threadIdx.x & 63;
  const int wave = threadIdx.x >> 6;
  const int tok0 = blockIdx.x * 16 + wave * 4;
  const float* xr = x + (size_t)tok0 * DIN;
  const float4* W4 = (const float4*)Wsel;

  float acc[4][8];
#pragma unroll
  for (int m = 0; m < 4; m++)
#pragma unroll
    for (int e = 0; e < 8; e++) acc[m][e] = 0.f;

#pragma unroll
  for (int i = 0; i < 16; i++) {
    const int d = lane + i * 64;
    const float4 wlo = W4[d * 2];
    const float4 whi = W4[d * 2 + 1];
#pragma unroll
    for (int m = 0; m < 4; m++) {
      const float xv = xr[m * DIN + d];
      acc[m][0] += xv * wlo.x; acc[m][1] += xv * wlo.y;
      acc[m][2] += xv * wlo.z; acc[m][3] += xv * wlo.w;
      acc[m][4] += xv * whi.x; acc[m][5] += xv * whi.y;
      acc[m][6] += xv * whi.z; acc[m][7] += xv * whi.w;
    }
  }
#pragma unroll
  for (int off = 32; off >= 1; off >>= 1)
#pragma unroll
    for (int m = 0; m < 4; m++)
#pragma unroll
      for (int e = 0; e < 8; e++) acc[m][e] += __shfl_xor(acc[m][e], off);

  if (lane < 4) {
    const int n = tok0 + lane;
    float w[8];
    float mx = -1e30f;
#pragma unroll
    for (int e = 0; e < 8; e++) { w[e] = acc[lane][e] + bsel[e]; mx = fmaxf(mx, w[e]); }
    float s = 0.f;
#pragma unroll
    for (int e = 0; e < 8; e++) { w[e] = expf(w[e] - mx); s += w[e]; }
    const float inv = 1.f / s;
#pragma unroll
    for (int e = 0; e < 8; e++) w[e] *= inv;

    float wsrt[8]; int ord[8];
    for (int k = 0; k < 8; k++) {
      const float v = w[k];
      int j = k;
      while (j > 0 && wsrt[j - 1] < v) { wsrt[j] = wsrt[j - 1]; ord[j] = ord[j - 1]; j--; }
      wsrt[j] = v; ord[j] = k;
    }
    float cum = 0.f, sws[8];
    for (int k = 0; k < 8; k++) {
      cum += wsrt[k];
      const float capped = fminf(cum, CAP);
      sws[k] = fmaxf(capped - cum + wsrt[k], 0.f);
    }
    for (int j = 0; j < 8; j++) sw[(size_t)n * 8 + j] = sws[ord[j]];
  }

  const float4* xr4 = (const float4*)xr;
  ushort4* xb4 = (ushort4*)(x_bf + (size_t)tok0 * DIN);
#pragma unroll
  for (int m = 0; m < 4; m++)
#pragma unroll
    for (int i = 0; i < 4; i++) {
      const int d4 = lane + i * 64;
      const float4 xv = xr4[m * 256 + d4];
      ushort4 p;
      p.x = bf16_bits(xv.x);
      p.y = bf16_bits(xv.y);
      p.z = bf16_bits(xv.z);
      p.w = bf16_bits(xv.w);
      xb4[m * 256 + d4] = p;
    }
}

// ---------------------------------------------------------------------------
// FUSED 1024-thread kernel: compaction FIRST (z==0, dispatch-ordered before
// the 4096 convert blocks so the 8-CU compact overlaps convert instead of
// trailing the whole grid), then weight transpose/convert (z in 1..16).
// ---------------------------------------------------------------------------
__global__ __launch_bounds__(1024) void compact_convert_kernel(
    const float* __restrict__ sw, int* __restrict__ idx, int* __restrict__ cnt,
    const float* __restrict__ W1, const float* __restrict__ W2,
    __hip_bfloat16* __restrict__ W1t, __hip_bfloat16* __restrict__ W2t)
{
  const int z = blockIdx.z;
  const int t = threadIdx.x;

  if (z == 0) {
    const int bid = blockIdx.x + 16 * blockIdx.y;
    if (bid >= 8) return;
    const int e = bid;
    const int lane = t & 63;
    const int wv = t >> 6;
    __shared__ int wave_base[16];
    __shared__ int chunk_total;
    int base = 0;
#pragma unroll
    for (int c = 0; c < 8; c++) {
      const int tok = c * 1024 + t;
      const bool act = sw[(size_t)tok * 8 + e] > 0.f;
      const unsigned long long m = __ballot(act);
      const int before = __popcll(m & ((1ull << lane) - 1ull));
      if (lane == 0) wave_base[wv] = __popcll(m);
      __syncthreads();
      if (t == 0) {
        int s = 0;
        for (int w = 0; w < 16; w++) { const int v = wave_base[w]; wave_base[w] = s; s += v; }
        chunk_total = s;
      }
      __syncthreads();
      if (act) idx[e * N_TOK + base + wave_base[wv] + before] = tok;
      base += chunk_total;
      __syncthreads();
    }
    if (t == 0) cnt[e] = base;
    return;
  }

  const int zz = z - 1;
  __shared__ unsigned short tile[64][65];
  const float* src = (zz & 8) ? W2 : W1;
  __hip_bfloat16* dst = (zz & 8) ? W2t : W1t;
  const int e = zz & 7;
  src += (size_t)e * 1024 * 1024;
  unsigned short* dstu = (unsigned short*)dst + (size_t)e * 1024 * 1024;
  const int R = blockIdx.y * 64, C = blockIdx.x * 64;

  {
    const int row = t >> 4;
    const int col4 = t & 15;
    const float4 v = *(const float4*)(src + (size_t)(R + row) * 1024 + C + col4 * 4);
    tile[row][col4 * 4 + 0] = bf16_bits(v.x);
    tile[row][col4 * 4 + 1] = bf16_bits(v.y);
    tile[row][col4 * 4 + 2] = bf16_bits(v.z);
    tile[row][col4 * 4 + 3] = bf16_bits(v.w);
  }
  __syncthreads();
  {
    const int d = t >> 4;
    const int j = t & 15;
    ushort4 o;
    o.x = tile[j * 4 + 0][d];
    o.y = tile[j * 4 + 1][d];
    o.z = tile[j * 4 + 2][d];
    o.w = tile[j * 4 + 3][d];
    *(ushort4*)(dstu + (size_t)(C + d) * 1024 + R + j * 4) = o;
  }
}

// ---------------------------------------------------------------------------
// PERSISTENT compacted grouped GEMM (round-9). Tile body = round-5-exact
// dbuf structure (best measured). 1024 persistent blocks (4/CU); each
// enumerates ACTIVE tiles only from cnt[] (prefix over ceil(cnt[e]/128) x 8
// n-blocks, block-uniform arithmetic, no atomics) and round-robins
// w += gridDim.x. Eliminates ~2560 zombie blocks, sustains ~4 resident
// blocks/CU (vs 2.2 measured with the 4096-block launch), and packs the
// tail (makespan ~= 2 tile-generations).
// r0-r8 model: per-block K-iter latency is fixed (~2200 cy in every variant
// incl. m97 itself); throughput = residency x work / latency. Residency is
// the only open lever.
// MODE 0 (FC1): A = gather(x_bf, idx[e]);  hpool[e] = bf16(relu(A W1t^T + b1))
// MODE 1 (FC2): A = hpool[e];  out[idx[e][m]] += sw * (A W2t^T + b2)  (atomic)
// ---------------------------------------------------------------------------
#define BUFO (128 * 32)   // elements per LDS buffer

template <int MODE>
__global__ __launch_bounds__(256, 2) void moe_gemm(
    const __hip_bfloat16* __restrict__ x_bf,
    __hip_bfloat16* __restrict__ hpool,
    const __hip_bfloat16* __restrict__ Wt,
    const float* __restrict__ biasAll,
    const float* __restrict__ sw,
    const int* __restrict__ idx, const int* __restrict__ cnt,
    float* __restrict__ out)
{
  __shared__ __align__(16) __hip_bfloat16 sA[2 * BUFO];
  __shared__ __align__(16) __hip_bfloat16 sB[2 * BUFO];

  // active-tile enumeration (block-uniform): pref[e] = first tile of expert e
  int pref[NE + 1];
  {
    int tot = 0;
#pragma unroll
    for (int ee = 0; ee < NE; ee++) {
      pref[ee] = tot;
      tot += ((cnt[ee] + 127) >> 7) * 8;   // m-tiles * 8 n-tiles
    }
    pref[NE] = tot;
  }
  const int total = pref[NE];

  const int t = threadIdx.x;
  const int lane = t & 63;
  const int wave = t >> 6;
  const int wm = (wave & 1) * 64;
  const int wn = (wave >> 1) * 64;
  const int sr = t >> 2;
  const int sc = (t & 3) * 8;
  const int rf = lane & 15;
  const int k8 = (lane >> 4) * 8;
  const int roA = (wm + rf) * 32 + k8;
  const int roB = (wn + rf) * 32 + k8;
  __hip_bfloat16* lA = &sA[sr * 32 + sc];
  __hip_bfloat16* lB = &sB[sr * 32 + sc];

  for (int w = blockIdx.x; w < total; w += gridDim.x) {
    int e = 0;
#pragma unroll
    for (int ee = 1; ee < NE; ee++) if (w >= pref[ee]) e = ee;
    const int local = w - pref[e];
    const int m0 = (local >> 3) * 128;
    const int n0 = (local & 7) * 128;
    const int count = cnt[e];
    const int* idx_e = idx + e * N_TOK;
    const float* bias = biasAll + e * 1024;

    floatx4 acc[4][4];
#pragma unroll
    for (int i = 0; i < 4; i++)
#pragma unroll
      for (int j = 0; j < 4; j++) acc[i][j] = (floatx4){0.f, 0.f, 0.f, 0.f};

    const __hip_bfloat16* Ag0;
    const __hip_bfloat16* Ag1;
    if (MODE == 0) {
      const int t0 = idx_e[min(m0 + sr, count - 1)];       // clamp tail
      const int t1 = idx_e[min(m0 + sr + 64, count - 1)];
      Ag0 = x_bf + (size_t)t0 * 1024 + sc;
      Ag1 = x_bf + (size_t)t1 * 1024 + sc;
    } else {
      const __hip_bfloat16* hp = hpool + (size_t)e * N_TOK * 1024;
      Ag0 = hp + (size_t)(m0 + sr) * 1024 + sc;            // tail: scratch, finite
      Ag1 = hp + (size_t)(m0 + sr + 64) * 1024 + sc;
    }
    const __hip_bfloat16* Bg = Wt + (size_t)e * 1024 * 1024 +
                               (size_t)(n0 + sr) * 1024 + sc;

    // prologue: stage K-tile 0 into buffer 0
    async_load16(Ag0, lA);
    async_load16(Ag1, lA + 64 * 32);
    async_load16(Bg, lB);
    async_load16(Bg + (size_t)64 * 1024, lB + 64 * 32);
    __syncthreads();

#define STEP(KT, RB, WB)                                                        \
    {                                                                           \
      const int knext = ((KT) + 1) * 32;                                        \
      if (knext < 1024) {                                                       \
        async_load16(Ag0 + knext, lA + (WB) * BUFO);                            \
        async_load16(Ag1 + knext, lA + (WB) * BUFO + 64 * 32);                  \
        async_load16(Bg + knext, lB + (WB) * BUFO);                             \
        async_load16(Bg + (size_t)64 * 1024 + knext, lB + (WB) * BUFO + 64*32); \
      }                                                                         \
      const __hip_bfloat16* pA = &sA[(RB) * BUFO + roA];                        \
      const __hip_bfloat16* pB = &sB[(RB) * BUFO + roB];                        \
      short8 aF[4], bF[4];                                                      \
      _Pragma("unroll")                                                         \
      for (int i = 0; i < 4; i++) aF[i] = *(const short8*)(pA + i * 16 * 32);   \
      _Pragma("unroll")                                                         \
      for (int j = 0; j < 4; j++) bF[j] = *(const short8*)(pB + j * 16 * 32);   \
      _Pragma("unroll")                                                         \
      for (int i = 0; i < 4; i++)                                               \
        _Pragma("unroll")                                                       \
        for (int j = 0; j < 4; j++)                                             \
          acc[i][j] = __builtin_amdgcn_mfma_f32_16x16x32_bf16(aF[i], bF[j],     \
                                                              acc[i][j], 0,0,0);\
      __syncthreads();                                                          \
    }

    for (int kt = 0; kt < 32; kt += 2) {
      STEP(kt, 0, 1);
      STEP(kt + 1, 1, 0);
    }
#undef STEP

    // epilogue: C/D layout col = lane&15, row = (lane>>4)*4 + reg
    const int quad = lane >> 4;
    const int cn = lane & 15;
#pragma unroll
    for (int i = 0; i < 4; i++) {
#pragma unroll
      for (int r = 0; r < 4; r++) {
        const int gm = m0 + wm + i * 16 + quad * 4 + r;
        if (gm >= count) continue;
        int tok = 0; float swv = 0.f;
        if (MODE == 1) {
          tok = idx_e[gm];
          swv = sw[tok * 8 + e];
        }
#pragma unroll
        for (int j = 0; j < 4; j++) {
          const int gn = n0 + wn + j * 16 + cn;
          const float v = acc[i][j][r] + bias[gn];
          if (MODE == 0) {
            hpool[((size_t)e * N_TOK + gm) * 1024 + gn] =
                __float2bfloat16(fmaxf(v, 0.f));
          } else {
            unsafeAtomicAdd(&out[(size_t)tok * 1024 + gn], swv * v);
          }
        }
      }
    }
    // no extra barrier needed: epilogue touches no LDS, and the K-loop's
    // final __syncthreads already separated all waves' LDS reads from the
    // next tile's staging writes.
  }
}

// ---------------------------------------------------------------------------
extern "C" void kernel_launch(void* const* d_in, const int* in_sizes, int n_in,
                              void* d_out, int out_size, void* d_ws, size_t ws_size,
                              hipStream_t stream) {
  const float* x    = (const float*)d_in[0];
  const float* Wsel = (const float*)d_in[1];
  const float* bsel = (const float*)d_in[2];
  const float* W1   = (const float*)d_in[3];
  const float* b1   = (const float*)d_in[4];
  const float* W2   = (const float*)d_in[5];
  const float* b2   = (const float*)d_in[6];
  float* out = (float*)d_out;

  char* ws = (char*)d_ws;
  __hip_bfloat16* x_bf = (__hip_bfloat16*)ws; ws += (size_t)N_TOK * DIN * 2;
  __hip_bfloat16* W1t  = (__hip_bfloat16*)ws; ws += (size_t)NE * DIN * HID * 2;
  __hip_bfloat16* W2t  = (__hip_bfloat16*)ws; ws += (size_t)NE * HID * DOUT * 2;
  float* sw            = (float*)ws;          ws += (size_t)N_TOK * NE * 4;
  int* idx             = (int*)ws;            ws += (size_t)NE * N_TOK * 4;
  int* cnt             = (int*)ws;            ws += 256;
  __hip_bfloat16* hpool = (__hip_bfloat16*)ws;  // NE*N_TOK*HID*2 = 134 MB

  selector_kernel<<<N_TOK / 16, 256, 0, stream>>>(x, Wsel, bsel, x_bf, sw,
                                                  (float4*)out);
  compact_convert_kernel<<<dim3(16, 16, 17), 1024, 0, stream>>>(
      sw, idx, cnt, W1, W2, W1t, W2t);

  moe_gemm<0><<<1024, 256, 0, stream>>>(
      x_bf, hpool, W1t, b1, sw, idx, cnt, out);
  moe_gemm<1><<<1024, 256, 0, stream>>>(
      x_bf, hpool, W2t, b2, sw, idx, cnt, out);
}